// Round 8
// baseline (381.921 us; speedup 1.0000x reference)
//
#include <hip/hip_runtime.h>
#include <hip/hip_bf16.h>
#include <math.h>

typedef __bf16 bf16;
typedef __attribute__((ext_vector_type(8))) __bf16 bf16x8;
typedef __attribute__((ext_vector_type(4))) __bf16 bf16x4;
typedef __attribute__((ext_vector_type(4))) float f32x4;

enum { EPI_PLAIN = 0, EPI_GELU = 1, EPI_RES = 2, EPI_GATE = 3 };

__device__ __forceinline__ void async16(const void* g, void* l) {
  __builtin_amdgcn_global_load_lds(
      (const __attribute__((address_space(1))) void*)g,
      (__attribute__((address_space(3))) void*)l, 16, 0, 0);
}

// barrier draining LDS ops but NOT the global_load_lds queue (vmcnt counted).
__device__ __forceinline__ void bar_lgkm() {
  asm volatile("s_waitcnt lgkmcnt(0)\n\ts_barrier" ::: "memory");
}

#define WAIT_VM(n) asm volatile("s_waitcnt vmcnt(" #n ")" ::: "memory")
#define MFMA16(d, va, vb) \
  d = __builtin_amdgcn_mfma_f32_16x16x32_bf16(va, vb, d, 0, 0, 0)

// ---------------------------------------------------------------------------
// Common epilogue element op.
template <typename CT, int EPI>
__device__ __forceinline__ void epi_store(
    CT* C, size_t idx, float v, int row, int col, const float* bias,
    const bf16* resid, const float* sup, const float* wsg, const float* bsg) {
  if constexpr (EPI == EPI_PLAIN) {
    C[idx] = (CT)v;
  } else if constexpr (EPI == EPI_GELU) {
    v += bias[col];
    float gl = 0.5f * v * (1.0f + erff(v * 0.70710678118654752f));
    C[idx] = (CT)gl;
  } else if constexpr (EPI == EPI_RES) {
    v += bias[col] + (float)resid[idx];
    C[idx] = (CT)v;
  } else {  // EPI_GATE
    v += bias[col];
    float g1 = 1.0f / (1.0f + expf(-v));
    float z = sup[row] * wsg[col] + bsg[col];
    float g2 = 1.0f / (1.0f + expf(-z));
    C[idx] = (CT)(g1 * g2);
  }
}

// ---------------------------------------------------------------------------
// gemm256: 256x128 tile, 8 waves in 4x2 grid of 64x64 wave tiles (R2's
// verified conflict-free shape at R4's wave count). LDS economy: 0.5 KB
// ds_read per MFMA (vs 0.75 R4 / 1.0 R7) -- attacks the measured ~45%-busy
// LDS unit. dbuf 48 KB -> 3 blocks/CU cap. Staging: 3 async16/thread
// (A rows srow/srow+128 + B srow), counted WAIT_VM(3). Read pattern and
// XOR involution byte-identical in form to the conflicts==0 configs.
// Used for G2 only (grid 64x12 = 768 = 3/CU balanced).
// ---------------------------------------------------------------------------
template <typename CT, int EPI>
__global__ __launch_bounds__(512, 2) void gemm256(
    const bf16* __restrict__ A, const bf16* __restrict__ B, CT* __restrict__ C,
    const float* __restrict__ bias, const bf16* __restrict__ resid,
    const float* __restrict__ sup, const float* __restrict__ wsg,
    const float* __restrict__ bsg, int M, int N, int K) {
  __shared__ bf16 As[2][256 * 32];  // 16 KB per buf
  __shared__ bf16 Bs[2][128 * 32];  // 8 KB per buf

  const int tid = threadIdx.x;
  const int nwg = gridDim.x;  // XCD-chunked remap (nwg % 8 == 0)
  const int cpx = nwg >> 3;
  const int wg = blockIdx.x;
  const int sw = (wg & 7) * cpx + (wg >> 3);
  const int ntn = N >> 7;
  const int bm = sw / ntn, bn = sw - bm * ntn;

  const int lane = tid & 63;
  const int wv = tid >> 6;
  const int wm = (wv >> 1) * 64, wn = (wv & 1) * 64;  // 4x2 wave grid
  const int quad = lane >> 4, l16 = lane & 15;
  const int slot8 = (quad ^ ((l16 >> 1) & 3)) * 8;  // HW-verified read swizzle

  f32x4 acc[4][4];
#pragma unroll
  for (int i = 0; i < 4; i++)
#pragma unroll
    for (int j = 0; j < 4; j++) acc[i][j] = f32x4{0.f, 0.f, 0.f, 0.f};

  // staging: thread covers A chunks tid (rows 0..127) and tid+512 (rows
  // 128..255; +128 keeps the parity class) and B chunk tid.
  const int srow = tid >> 2;
  const int sq8 = ((tid & 3) ^ ((srow >> 1) & 3)) * 8;
  const bf16* pa0 = A + (size_t)(bm * 256 + srow) * K + sq8;
  const bf16* pa1 = pa0 + (size_t)128 * K;
  const bf16* pb = B + (size_t)(bn * 128 + srow) * K + sq8;
  bf16* dA0 = &As[0][0] + wv * 512;         // chunks wv*64..: elem c*8
  bf16* dA1 = &As[0][0] + 4096 + wv * 512;  // chunks 512+..
  bf16* dB = &Bs[0][0] + wv * 512;

  auto stg = [&](int buf) {
    async16(pa0, dA0 + buf * 8192);
    async16(pa1, dA1 + buf * 8192);
    async16(pb, dB + buf * 4096);
    pa0 += 32; pa1 += 32; pb += 32;
  };

  stg(0);  // prologue: tile 0 in flight (3 loads/thread)

  const int nt = K >> 5;
  for (int t = 0; t < nt; ++t) {
    const int cur = t & 1;
    if (t + 1 < nt) {
      stg(cur ^ 1);  // next tile first
      WAIT_VM(3);    // tile t landed; t+1's 3 stay in flight
    } else {
      WAIT_VM(0);
    }
    bar_lgkm();

    bf16x8 af[4], bfr[4];
#pragma unroll
    for (int i = 0; i < 4; i++)
      af[i] = *(const bf16x8*)&As[cur][(wm + i * 16 + l16) * 32 + slot8];
#pragma unroll
    for (int j = 0; j < 4; j++)
      bfr[j] = *(const bf16x8*)&Bs[cur][(wn + j * 16 + l16) * 32 + slot8];
#pragma unroll
    for (int i = 0; i < 4; i++)
#pragma unroll
      for (int j = 0; j < 4; j++) MFMA16(acc[i][j], af[i], bfr[j]);
    bar_lgkm();
  }

#pragma unroll
  for (int i = 0; i < 4; i++) {
    const int row0 = bm * 256 + wm + i * 16 + quad * 4;
#pragma unroll
    for (int j = 0; j < 4; j++) {
      const int col = bn * 128 + wn + j * 16 + l16;
#pragma unroll
      for (int r = 0; r < 4; r++) {
        const int row = row0 + r;
        epi_store<CT, EPI>(C, (size_t)row * N + col, acc[i][j][r], row, col,
                           bias, resid, sup, wsg, bsg);
      }
    }
  }
}

// ---------------------------------------------------------------------------
// gemm128: R4 structure verbatim (128x128, 8 waves of 64x32, G2=71us-class,
// conflicts 0, occ 64%) + optional AFP32: A staged from fp32 in-kernel
// (2 f32x4 loads + convert + ds_write_b128 to the linear chunk the DMA
// would write; ledger 2f+1B per tile -> counted WAIT_VM(3)). Kills cvtx.
// ---------------------------------------------------------------------------
template <typename CT, int EPI, int AFP32>
__global__ __launch_bounds__(512, 2) void gemm128(
    const bf16* __restrict__ A, const float* __restrict__ Af,
    const bf16* __restrict__ B, CT* __restrict__ C,
    const float* __restrict__ bias, const bf16* __restrict__ resid,
    const float* __restrict__ sup, const float* __restrict__ wsg,
    const float* __restrict__ bsg, int M, int N, int K) {
  __shared__ bf16 As[2][128 * 32];
  __shared__ bf16 Bs[2][128 * 32];

  const int tid = threadIdx.x;
  const int nwg = gridDim.x;
  const int cpx = nwg >> 3;
  const int wg = blockIdx.x;
  const int sw = (wg & 7) * cpx + (wg >> 3);
  const int ntn = N >> 7;
  const int bm = sw / ntn, bn = sw - bm * ntn;

  const int lane = tid & 63;
  const int wv = tid >> 6;
  const int wm = (wv >> 2) * 64, wn = (wv & 3) * 32;  // 2x4 wave grid
  const int quad = lane >> 4, l16 = lane & 15;
  const int slot8 = (quad ^ ((l16 >> 1) & 3)) * 8;

  f32x4 acc[4][2];
#pragma unroll
  for (int i = 0; i < 4; i++)
#pragma unroll
    for (int j = 0; j < 2; j++) acc[i][j] = f32x4{0.f, 0.f, 0.f, 0.f};

  const int srow = tid >> 2;
  const int sq8 = ((tid & 3) ^ ((srow >> 1) & 3)) * 8;
  const bf16* pb = B + (size_t)(bn * 128 + srow) * K + sq8;
  bf16* dB = &Bs[0][0] + wv * 512;

  auto compute = [&](int buf) {
    bf16x8 af[4], bfr[2];
#pragma unroll
    for (int i = 0; i < 4; i++)
      af[i] = *(const bf16x8*)&As[buf][(wm + i * 16 + l16) * 32 + slot8];
#pragma unroll
    for (int j = 0; j < 2; j++)
      bfr[j] = *(const bf16x8*)&Bs[buf][(wn + j * 16 + l16) * 32 + slot8];
#pragma unroll
    for (int i = 0; i < 4; i++) {
      MFMA16(acc[i][0], af[i], bfr[0]);
      MFMA16(acc[i][1], af[i], bfr[1]);
    }
  };

  const int nt = K >> 5;  // even (24 or 48)

  if constexpr (!AFP32) {
    const bf16* pa = A + (size_t)(bm * 128 + srow) * K + sq8;
    bf16* dA = &As[0][0] + wv * 512;
    auto stg = [&](int buf) {
      async16(pa, dA + buf * 4096);
      async16(pb, dB + buf * 4096);
      pa += 32; pb += 32;
    };
    stg(0);
    for (int t = 0; t < nt; ++t) {
      const int cur = t & 1;
      if (t + 1 < nt) {
        stg(cur ^ 1);
        WAIT_VM(2);
      } else {
        WAIT_VM(0);
      }
      bar_lgkm();
      compute(cur);
      bar_lgkm();
    }
  } else {
    // fp32-A path (G1): per tile, thread loads 2xf32x4 from the pre-swizzled
    // source, converts to one bf16x8, ds_writes the linear chunk; B by DMA.
    const float* pf = Af + (size_t)(bm * 128 + srow) * K + sq8;
    bf16* wrA = &As[0][0] + tid * 8;
    f32x4 fE0, fE1, fO0, fO1;

    // prologue: tile 0 (2 f-loads + 1 B-DMA) in flight
    fE0 = *(const f32x4*)pf;
    fE1 = *(const f32x4*)(pf + 4);
    async16(pb, dB);

    auto step = [&](int buf, f32x4& c0, f32x4& c1, f32x4& n0, f32x4& n1, int t) {
      if (t + 1 < nt) {
        const float* p = pf + (size_t)(t + 1) * 32;
        n0 = *(const f32x4*)p;
        n1 = *(const f32x4*)(p + 4);
        async16(pb + (size_t)(t + 1) * 32, dB + (buf ^ 1) * 4096);
        WAIT_VM(3);  // tile t's {2f,1B} retired; t+1's 3 stay in flight
      } else {
        WAIT_VM(0);
      }
      bf16x8 v;
      v[0] = (bf16)c0[0]; v[1] = (bf16)c0[1]; v[2] = (bf16)c0[2]; v[3] = (bf16)c0[3];
      v[4] = (bf16)c1[0]; v[5] = (bf16)c1[1]; v[6] = (bf16)c1[2]; v[7] = (bf16)c1[3];
      *(bf16x8*)(wrA + buf * 4096) = v;  // ds_write_b128, linear chunk
      bar_lgkm();  // ds_writes drained + staging of tile t visible
      compute(buf);
      bar_lgkm();
    };

    for (int t = 0; t < nt; t += 2) {
      step(0, fE0, fE1, fO0, fO1, t);
      step(1, fO0, fO1, fE0, fE1, t + 1);
    }
  }

#pragma unroll
  for (int i = 0; i < 4; i++) {
    const int row0 = bm * 128 + wm + i * 16 + quad * 4;
#pragma unroll
    for (int j = 0; j < 2; j++) {
      const int col = bn * 128 + wn + j * 16 + l16;
#pragma unroll
      for (int r = 0; r < 4; r++) {
        const int row = row0 + r;
        epi_store<CT, EPI>(C, (size_t)row * N + col, acc[i][j][r], row, col,
                           bias, resid, sup, wsg, bsg);
      }
    }
  }
}

// ---------------- chunked parallel scan ----------------
constexpr int SC_CH = 32, SC_NCH = 16, SC_CW = 32;

__global__ __launch_bounds__(512) void scan2_kernel(const float* __restrict__ g,
                                                    const bf16* __restrict__ xt,
                                                    bf16* __restrict__ s, int T, int C) {
  __shared__ float lA[SC_NCH][SC_CW];
  __shared__ float lB[SC_NCH][SC_CW];
  __shared__ float lC[SC_NCH][SC_CW];
  const int cl = threadIdx.x & (SC_CW - 1);
  const int ch = threadIdx.x / SC_CW;
  const int c = blockIdx.x * SC_CW + cl;
  const int n = blockIdx.y;
  const size_t base = ((size_t)n * T + ch * SC_CH) * C + c;

  float a_arr[SC_CH], sl[SC_CH];
  float A = 1.f, B = 0.f;
#pragma unroll
  for (int t = 0; t < SC_CH; ++t) {
    size_t idx = base + (size_t)t * C;
    float gv = g[idx], xv = (float)xt[idx];
    float at = 1.0f - gv;
    a_arr[t] = at;
    B = at * B + gv * xv;
    sl[t] = B;
    A *= at;
  }
  lA[ch][cl] = A;
  lB[ch][cl] = B;
  __syncthreads();
  if (ch == 0) {
    float carry = 0.f;
#pragma unroll
    for (int j = 0; j < SC_NCH; ++j) {
      lC[j][cl] = carry;
      carry = lA[j][cl] * carry + lB[j][cl];
    }
  }
  __syncthreads();
  const float carry = lC[ch][cl];
  float P = 1.f;
#pragma unroll
  for (int t = 0; t < SC_CH; ++t) {
    P *= a_arr[t];
    s[base + (size_t)t * C] = (bf16)(sl[t] + P * carry);
  }
}

// ---------------- weight converts (fused 5-way, scalar) ----------------
__global__ __launch_bounds__(256) void cvt5_kernel(
    const float* s0, bf16* d0, int n0, const float* s1, bf16* d1, int n1,
    const float* s2, bf16* d2, int n2, const float* s3, bf16* d3, int n3,
    const float* s4, bf16* d4, int n4) {
  const float* s; bf16* d; int n;
  switch (blockIdx.y) {
    case 0: s = s0; d = d0; n = n0; break;
    case 1: s = s1; d = d1; n = n1; break;
    case 2: s = s2; d = d2; n = n2; break;
    case 3: s = s3; d = d3; n = n3; break;
    default: s = s4; d = d4; n = n4; break;
  }
  int i = blockIdx.x * 256 + threadIdx.x;
  if (i < n) d[i] = (bf16)s[i];
}

extern "C" void kernel_launch(void* const* d_in, const int* in_sizes, int n_in,
                              void* d_out, int out_size, void* d_ws, size_t ws_size,
                              hipStream_t stream) {
  const float* x_seq = (const float*)d_in[0];
  const float* sup = (const float*)d_in[1];
  const float* W_in = (const float*)d_in[2];
  const float* W_out = (const float*)d_in[3];
  const float* W_bg = (const float*)d_in[4];
  const float* b_bg = (const float*)d_in[5];
  const float* W_sg = (const float*)d_in[6];
  const float* b_sg = (const float*)d_in[7];
  const float* W_f1 = (const float*)d_in[8];
  const float* b_f1 = (const float*)d_in[9];
  const float* W_f2 = (const float*)d_in[10];
  const float* b_f2 = (const float*)d_in[11];

  const int Nb = 32, T = 512, C = 768, H = 1536;
  const int M = Nb * T;  // 16384

  char* ws = (char*)d_ws;
  size_t off = 0;
  auto alloc = [&](size_t bytes) {
    void* p = ws + off;
    off += (bytes + 255) & ~(size_t)255;
    return p;
  };
  bf16* Win_bf = (bf16*)alloc((size_t)C * C * 2);
  bf16* Wf1_bf = (bf16*)alloc((size_t)H * C * 2);
  bf16* Wf2_bf = (bf16*)alloc((size_t)C * H * 2);
  bf16* Wbg_bf = (bf16*)alloc((size_t)C * C * 2);
  bf16* Wout_bf = (bf16*)alloc((size_t)C * C * 2);
  bf16* x_bf = (bf16*)alloc((size_t)M * C * 2);  // x; reused as s after G3
  bf16* h_bf = (bf16*)alloc((size_t)M * H * 2);
  bf16* xt_bf = (bf16*)alloc((size_t)M * C * 2);
  float* g_f = (float*)alloc((size_t)M * C * 4);
  bf16* s_bf = x_bf;  // x dead after G3

  cvt5_kernel<<<dim3((H * C + 255) / 256, 5), 256, 0, stream>>>(
      W_in, Win_bf, C * C, W_f1, Wf1_bf, H * C, W_f2, Wf2_bf, C * H,
      W_bg, Wbg_bf, C * C, W_out, Wout_bf, C * C);

  dim3 blk(512);
  // All grids = 768 blocks = 3/CU balanced; nwg % 8 == 0 (XCD remap).
  // G1: x = x_seq @ W_in^T  (A staged from fp32 in-kernel; no cvtx pass)
  gemm128<bf16, EPI_PLAIN, 1><<<dim3((M / 128) * (C / 128)), blk, 0, stream>>>(
      nullptr, x_seq, Win_bf, x_bf, nullptr, nullptr, nullptr, nullptr, nullptr, M, C, C);
  // G2: h = gelu(x @ W_f1^T + b_f1)  -- 256x128 tile, 64x64 wave tiles
  gemm256<bf16, EPI_GELU><<<dim3((M / 256) * (H / 128)), blk, 0, stream>>>(
      x_bf, Wf1_bf, h_bf, b_f1, nullptr, nullptr, nullptr, nullptr, M, H, C);
  // G3: xt = x + h @ W_f2^T + b_f2
  gemm128<bf16, EPI_RES, 0><<<dim3((M / 128) * (C / 128)), blk, 0, stream>>>(
      h_bf, nullptr, Wf2_bf, xt_bf, b_f2, x_bf, nullptr, nullptr, nullptr, M, C, H);
  // G4: g = sigmoid(xt @ W_bg^T + b_bg) * sigmoid(sup*W_sg + b_sg)  (fp32 out)
  gemm128<float, EPI_GATE, 0><<<dim3((M / 128) * (C / 128)), blk, 0, stream>>>(
      xt_bf, nullptr, Wbg_bf, g_f, b_bg, nullptr, sup, W_sg, b_sg, M, C, C);
  // scan
  scan2_kernel<<<dim3(C / SC_CW, Nb), dim3(SC_CW * SC_NCH), 0, stream>>>(
      g_f, xt_bf, s_bf, T, C);
  // G6: out = s @ W_out^T (fp32 out)
  gemm128<float, EPI_PLAIN, 0><<<dim3((M / 128) * (C / 128)), blk, 0, stream>>>(
      s_bf, nullptr, Wout_bf, (float*)d_out, nullptr, nullptr, nullptr, nullptr, nullptr, M, C, C);
}